// Round 14
// baseline (3723.438 us; speedup 1.0000x reference)
//
#include <hip/hip_runtime.h>
#include <math.h>

// DistillerGRU: T=512, B=64, H=1024, 2 layers.
// R14 = R12 (proven flag protocol, 2634us) + L2-cached h data path:
//  - h/hist READS are plain loads behind a per-step ACQUIRE fence ("agent" ->
//    L1+L2 invalidate). R12/R13 counters showed agent-scope data loads served
//    from HBM (2.2MB/step FETCH): bypassing L2 cost a 32x broadcast
//    amplification. Plain loads + inv let same-XCD WGs share one L2 refill.
//  - h/hist/flags WRITES stay agent-scope (land below L2 -> refills fresh).
//  - Wave-split flag polls: wave0 polls its K-half's 32 producer flags only.
//  - 8 groups of 32 WGs (layer x batch-quarter); per-wave early flags;
//    L0->L1 32-slot hist ring + lazy back-pressure. Fence also at t=0
//    (graph-replay stale-L2 hazard).

#define TT 512
#define BB 64
#define HH 1024
#define NWG 256
#define NBH (BB * HH)
#define RING 32

typedef _Float16 half8 __attribute__((ext_vector_type(8)));
typedef _Float16 f16x4 __attribute__((ext_vector_type(4)));
typedef float f32x4 __attribute__((ext_vector_type(4)));
typedef unsigned int u32x4 __attribute__((ext_vector_type(4)));
typedef unsigned long long u64;

#define MFMA16 __builtin_amdgcn_mfma_f32_16x16x32_f16

// ---------------- asm memory helpers (64-bit VGPR-address form) ----------------
__device__ inline u32x4 ldq_plain(const void* p) {
  u32x4 r; u64 a = (u64)(uintptr_t)p;
  asm volatile("global_load_dwordx4 %0, %1, off" : "=v"(r) : "v"(a));
  return r;
}
__device__ inline unsigned ldflag(const void* p) {   // agent-scope flag read
  unsigned r; u64 a = (u64)(uintptr_t)p;
  asm volatile("global_load_dword %0, %1, off sc0 sc1\n\ts_waitcnt vmcnt(0)"
               : "=v"(r) : "v"(a) : "memory");
  return r;
}
__device__ inline void stw(void* p, unsigned v) {    // agent-scope store
  u64 a = (u64)(uintptr_t)p;
  asm volatile("global_store_dword %0, %1, off sc0 sc1" :: "v"(a), "v"(v) : "memory");
}
__device__ inline void vdrain() { asm volatile("s_waitcnt vmcnt(0)" ::: "memory"); }

__device__ inline float fast_sigmoid(float x) { return 1.f / (1.f + __expf(-x)); }
__device__ inline float fast_tanh(float x) {
  float e = __expf(2.f * x);
  return 1.f - 2.f / (e + 1.f);
}
__device__ inline void backoff_sleep(int sl) {   // literal-only s_sleep
  if (sl <= 0) __builtin_amdgcn_s_sleep(1);
  else if (sl == 1) __builtin_amdgcn_s_sleep(2);
  else if (sl == 2) __builtin_amdgcn_s_sleep(4);
  else __builtin_amdgcn_s_sleep(8);
}

// ---------------- prologue kernels ----------------
__global__ void cvt_f32_f16_kernel(const float* __restrict__ src,
                                   _Float16* __restrict__ dst, long n) {
  long i = ((long)blockIdx.x * blockDim.x + threadIdx.x) * 4;
  long stride = (long)gridDim.x * blockDim.x * 4;
  for (long e = i; e < n; e += stride) {
    float4 v = *(const float4*)(src + e);
    f16x4 h;
    h.x = (_Float16)v.x; h.y = (_Float16)v.y;
    h.z = (_Float16)v.z; h.w = (_Float16)v.w;
    *(f16x4*)(dst + e) = h;
  }
}

// wp[tile(192)][kst(64)][lane(64)][8]; element = W[tile*16+(lane&15)][k],
// k = kst*32 + (lane>>4)*8 + sub; kst<32 from Wh, kst>=32 from Wx.
__global__ void cvt_wpack_kernel(const float* __restrict__ Wh,
                                 const float* __restrict__ Wx,
                                 _Float16* __restrict__ wp) {
  int gid = blockIdx.x * 256 + threadIdx.x;
  int lane = gid & 63;
  int kst = (gid >> 6) & 63;
  int tile = gid >> 12;
  int g = tile * 16 + (lane & 15);
  int ko = (lane >> 4) * 8;
  const float* src = (kst < 32) ? (Wh + (long)g * HH + kst * 32 + ko)
                                : (Wx + (long)g * HH + (kst - 32) * 32 + ko);
  half8 h;
#pragma unroll
  for (int j = 0; j < 8; ++j) h[j] = (_Float16)src[j];
  *(half8*)(wp + (((long)tile * 64 + kst) * 64 + lane) * 8) = h;
}

__global__ void init_hf_kernel(const float* __restrict__ h0,
                               _Float16* __restrict__ h0loc,
                               _Float16* __restrict__ h1loc) {
  int i = blockIdx.x * 256 + threadIdx.x;  // grid = 2*B*H/256
  float v = h0[i];
  if (i < NBH) h0loc[i] = (_Float16)v;
  else         h1loc[i - NBH] = (_Float16)v;
}

__global__ void sentinel_kernel(float* out) { out[0] = 12345.0f; }

// ---------------- persistent 2-layer GRU ----------------
__global__ __launch_bounds__(256, 1) void gru_persist(
    const _Float16* __restrict__ x16,
    const _Float16* __restrict__ w0p, const _Float16* __restrict__ w1p,
    const float* __restrict__ bx0, const float* __restrict__ bh0,
    const float* __restrict__ bx1, const float* __restrict__ bh1,
    const float* __restrict__ h0in,
    _Float16* __restrict__ h0loc, _Float16* __restrict__ h1loc,
    _Float16* __restrict__ hist,
    float* __restrict__ out, unsigned* __restrict__ bar)
{
  const int tid = threadIdx.x;
  const int wid = tid >> 6, lane = tid & 63;
  const int wg = blockIdx.x;
  const int lcol = lane & 15;
  const int lk = (lane >> 4) * 8;

  const int grp = wg >> 5;          // 0..7
  const int layer = grp >> 2;
  const int q = grp & 3;
  const int rank = wg & 31;

  __shared__ u32x4 wlds[4][6][4][64];   // 96KB: per-wave kst 12..15 weights
  __shared__ f32x4 red[4][6][64];       // 24KB
  __shared__ f32x4 yshare[2][64];       // 2KB

  unsigned* myf  = bar + grp * 1024;            // 64 slots x 64B stride
  unsigned* l0if = bar + 8192 + q * 1024;       // ring-valid flags (32 slots)
  unsigned* prog = bar + 12288 + q * 1024;      // L1 progress (32 slots)

  // ---- weights: WG owns 32 cols (2 col-tiles) x 3 gates = 6 tiles ----
  const _Float16* wf = layer ? w1p : w0p;
  _Float16* hloc = layer ? h1loc : h0loc;
  half8 wb[6][12];
#pragma unroll
  for (int i = 0; i < 6; ++i) {
    const long tile = (long)((i >> 1) * 64 + rank * 2 + (i & 1));
#pragma unroll
    for (int ks = 0; ks < 12; ++ks)
      wb[i][ks] = *(const half8*)(wf + (tile * 64 + (wid * 16 + ks)) * 512 + lane * 8);
#pragma unroll
    for (int jj = 0; jj < 4; ++jj)
      wlds[wid][i][jj][lane] = *(const u32x4*)(wf + (tile * 64 + (wid * 16 + 12 + jj)) * 512 + lane * 8);
  }

  const int er0 = q * 16 + (lane >> 4) * 4;     // 4 batch rows (global row ids)
  const int col = rank * 32 + wid * 16 + lcol;  // valid for wid<2
  float rbv = 0.f, zbv = 0.f, nhb = 0.f, nxb = 0.f;
  float hreg[4] = {0.f, 0.f, 0.f, 0.f};
  if (wid < 2) {
    const float* bx = layer ? bx1 : bx0;
    const float* bhp = layer ? bh1 : bh0;
    rbv = bhp[col] + bx[col];
    zbv = bhp[HH + col] + bx[HH + col];
    nhb = bhp[2 * HH + col];
    nxb = bx[2 * HH + col];
#pragma unroll
    for (int j = 0; j < 4; ++j)
      hreg[j] = h0in[layer * NBH + (er0 + j) * HH + col];
  }
  __syncthreads();   // wlds ready

  // per-lane byte offset of this wave's A-fragment chunk 0
  const long aoff = (long)(((q * 16 + lcol) * HH) + (wid & 1) * 512 + lk) * 2;

  int lb = 0;   // wave2(L0): lazy lower bound on L1 progress
  for (int t = 0; t < TT; ++t) {
    const int rd = t & 1;
    u32x4 ab[16];

    if (wid < 2) {
      // ---- wait: this wave's K-half producers (ranks wid*16..wid*16+15,
      // flag slots wid*32..wid*32+31) finished step t-1 ----
      if (t > 0) {
        for (;;) {
          unsigned f = ldflag(myf + (wid * 32 + (lane & 31)) * 16);
          if (__ballot((int)f >= t) == ~0ull) break;
          __builtin_amdgcn_s_sleep(1);
        }
      }
      // acquire: invalidate L1+L2 so plain loads refill fresh data (also at
      // t=0: prior graph replay may have left stale h lines in L2)
      __builtin_amdgcn_fence(__ATOMIC_ACQUIRE, "agent");
      const char* ap = (const char*)(hloc + (long)rd * NBH) + aoff;
#pragma unroll
      for (int ks = 0; ks < 16; ++ks) ab[ks] = ldq_plain(ap + ks * 64);
    } else if (layer == 0) {
      const char* ap = (const char*)(x16 + (long)t * NBH) + aoff;
#pragma unroll
      for (int ks = 0; ks < 16; ++ks) ab[ks] = ldq_plain(ap + ks * 64);
    } else {
      // y0[t] = hist slot t+1: poll this wave's half of producer flags
      for (;;) {
        unsigned f = ldflag(l0if + ((wid - 2) * 16 + lcol) * 16);
        if (__ballot((int)f >= t + 1) == ~0ull) break;
        __builtin_amdgcn_s_sleep(1);
      }
      __builtin_amdgcn_fence(__ATOMIC_ACQUIRE, "agent");
      const char* ap = (const char*)(hist + (long)((t + 1) & (RING - 1)) * NBH) + aoff;
#pragma unroll
      for (int ks = 0; ks < 16; ++ks) ab[ks] = ldq_plain(ap + ks * 64);
    }
    asm volatile("s_waitcnt vmcnt(0)" ::: "memory");
    __builtin_amdgcn_sched_barrier(0);

    // ---- 96 MFMAs: 6 tiles x 16 ks ----
    f32x4 acc[6] = {};
#pragma unroll
    for (int ks = 0; ks < 12; ++ks) {
      half8 a = __builtin_bit_cast(half8, ab[ks]);
#pragma unroll
      for (int i = 0; i < 6; ++i) acc[i] = MFMA16(a, wb[i][ks], acc[i], 0, 0, 0);
    }
#pragma unroll
    for (int jj = 0; jj < 4; ++jj) {
      half8 a = __builtin_bit_cast(half8, ab[12 + jj]);
#pragma unroll
      for (int i = 0; i < 6; ++i)
        acc[i] = MFMA16(a, __builtin_bit_cast(half8, wlds[wid][i][jj][lane]), acc[i], 0, 0, 0);
    }
#pragma unroll
    for (int i = 0; i < 6; ++i) red[wid][i][lane] = acc[i];
    __syncthreads();   // (A)

    if (wid < 2) {
      const int h = wid;   // col-tile this wave finishes
      f32x4 rs = red[0][h][lane] + red[1][h][lane] + red[2][h][lane] + red[3][h][lane];
      f32x4 zs = red[0][2 + h][lane] + red[1][2 + h][lane] + red[2][2 + h][lane] + red[3][2 + h][lane];
      f32x4 nh = red[0][4 + h][lane] + red[1][4 + h][lane];
      f32x4 nx = red[2][4 + h][lane] + red[3][4 + h][lane];
      char* hdst = (char*)(hloc + (long)(rd ^ 1) * NBH);
      f32x4 hnv;
#pragma unroll
      for (int j = 0; j < 4; ++j) {
        const float rg = fast_sigmoid(rs[j] + rbv);
        const float zg = fast_sigmoid(zs[j] + zbv);
        const float ng = fast_tanh(nx[j] + nxb + rg * (nh[j] + nhb));
        const float hn = (1.f - zg) * ng + zg * hreg[j];
        hreg[j] = hn; hnv[j] = hn;
      }
      yshare[h][lane] = hnv;
#pragma unroll
      for (int j = 0; j < 4; ++j) {
        _Float16 hf = (_Float16)hnv[j];
        unsigned us = (unsigned)__builtin_bit_cast(unsigned short, hf);
        unsigned other = (unsigned)__shfl_xor((int)us, 1);
        if ((lane & 1) == 0)
          stw(hdst + (long)(((er0 + j) * HH) + col) * 2, us | (other << 16));
      }
      vdrain();                          // h-stores visible below L2
      if (lane == 0)
        stw(myf + (rank * 2 + wid) * 16, (unsigned)(t + 1));   // EARLY flag
    }
    __syncthreads();   // (B): yshare visible for waves 2/3

    if (layer == 0) {
      if (wid == 2) {
        // ring stores of step t-1 already drained by this step's load-wait
        stw(l0if + rank * 16, (unsigned)t);                // slots <= t valid
        if (t >= RING - 1) {                               // lazy back-pressure
          const int need = t - (RING - 1);
          if (lb < need) {
            int sl = 0;
            for (;;) {
              unsigned f = ldflag(prog + (lane & 31) * 16);
              if (__ballot((int)f >= need + 16) == ~0ull) { lb = need + 16; break; }
              if (__ballot((int)f >= need) == ~0ull) { lb = need; break; }
              backoff_sleep(sl); ++sl;
            }
          }
        }
        char* rbase = (char*)(hist + (long)((t + 1) & (RING - 1)) * NBH);
#pragma unroll
        for (int h2 = 0; h2 < 2; ++h2) {
          f32x4 v = yshare[h2][lane];
          const int coln = rank * 32 + h2 * 16 + lcol;
#pragma unroll
          for (int j = 0; j < 4; ++j) {
            _Float16 hf = (_Float16)v[j];
            unsigned us = (unsigned)__builtin_bit_cast(unsigned short, hf);
            unsigned other = (unsigned)__shfl_xor((int)us, 1);
            if ((lane & 1) == 0)
              stw(rbase + (long)(((er0 + j) * HH) + coln) * 2, us | (other << 16));
          }
        }
      }
    } else {
      if (wid == 2 && lane == 0)
        stw(prog + rank * 16, (unsigned)t);                // L1 progress
      if (wid == 3) {
        float* yo = out + (long)t * NBH;
#pragma unroll
        for (int h2 = 0; h2 < 2; ++h2) {
          f32x4 v = yshare[h2][lane];
          const int coln = rank * 32 + h2 * 16 + lcol;
#pragma unroll
          for (int j = 0; j < 4; ++j) yo[(er0 + j) * HH + coln] = v[j];
        }
      }
    }
  }

  if (layer == 0 && wid == 2) {          // certify final hist slot
    vdrain();
    stw(l0if + rank * 16, (unsigned)TT);
  }
  if (wid < 2) {                         // final hidden states (f32 master)
#pragma unroll
    for (int j = 0; j < 4; ++j)
      out[(long)TT * NBH + (long)layer * NBH + (er0 + j) * HH + col] = hreg[j];
  }
}

// ---------------- launch ----------------
extern "C" void kernel_launch(void* const* d_in, const int* in_sizes, int n_in,
                              void* d_out, int out_size, void* d_ws, size_t ws_size,
                              hipStream_t stream) {
  const float* x   = (const float*)d_in[0];
  const float* h0  = (const float*)d_in[1];
  const float* Wx0 = (const float*)d_in[2];
  const float* bx0 = (const float*)d_in[3];
  const float* Wh0 = (const float*)d_in[4];
  const float* bh0 = (const float*)d_in[5];
  const float* Wx1 = (const float*)d_in[6];
  const float* bx1 = (const float*)d_in[7];
  const float* Wh1 = (const float*)d_in[8];
  const float* bh1 = (const float*)d_in[9];
  float* out = (float*)d_out;

  const long nTBH = (long)TT * BB * HH;
  const long nWP  = (long)192 * 64 * 64 * 8;

  char* p = (char*)d_ws;
  _Float16* x16   = (_Float16*)p;  p += nTBH * 2;              // 67.1 MB
  _Float16* w0p   = (_Float16*)p;  p += nWP * 2;               // 12.6 MB
  _Float16* w1p   = (_Float16*)p;  p += nWP * 2;               // 12.6 MB
  _Float16* hist  = (_Float16*)p;  p += (long)RING * NBH * 2;  // 4.2 MB
  _Float16* h0loc = (_Float16*)p;  p += 2 * (long)NBH * 2;     // 256 KB
  _Float16* h1loc = (_Float16*)p;  p += 2 * (long)NBH * 2;     // 256 KB
  unsigned* bar   = (unsigned*)p;  p += 65536;                 // 64 KB flags
  if ((size_t)(p - (char*)d_ws) > ws_size) {
    sentinel_kernel<<<1, 1, 0, stream>>>(out);
    return;
  }

  (void)hipMemsetAsync(bar, 0, 65536, stream);
  cvt_f32_f16_kernel<<<2048, 256, 0, stream>>>(x, x16, nTBH);
  cvt_wpack_kernel<<<3072, 256, 0, stream>>>(Wh0, Wx0, w0p);
  cvt_wpack_kernel<<<3072, 256, 0, stream>>>(Wh1, Wx1, w1p);
  init_hf_kernel<<<512, 256, 0, stream>>>(h0, h0loc, h1loc);

  void* args[] = {(void*)&x16, (void*)&w0p, (void*)&w1p,
                  (void*)&bx0, (void*)&bh0, (void*)&bx1, (void*)&bh1,
                  (void*)&h0, (void*)&h0loc, (void*)&h1loc, (void*)&hist,
                  (void*)&out, (void*)&bar};
  hipError_t e = hipLaunchCooperativeKernel((const void*)gru_persist,
                                            dim3(NWG), dim3(256), args, 0, stream);
  if (e != hipSuccess) {
    // 256 WGs at 1 WG/CU: co-resident on an idle device even without coop.
    gru_persist<<<NWG, 256, 0, stream>>>(x16, w0p, w1p, bx0, bh0, bx1, bh1,
                                         h0, h0loc, h1loc, hist, out, bar);
  }
}

// Round 16
// 2634.588 us; speedup vs baseline: 1.4133x; 1.4133x over previous
//
#include <hip/hip_runtime.h>
#include <math.h>

// DistillerGRU: T=512, B=64, H=1024, 2 layers.
// R16 = R12 restored verbatim (verified best: 2634us, PASS, absmax 0.0039).
// R12: persistent cooperative kernel, agent-scope flag protocol.
//  - 8 groups of 32 WGs: (layer, batch-quarter). Batch rows independent ->
//    groups fully decoupled except one-way L0->L1 ring.
//  - Per WG: 16 batch rows x 32 h-cols (2 col-tiles x 3 gates = 6 MFMA tiles
//    per wave); 4 waves split K=2048; weights 12 K-steps VGPR + 4 LDS.
//  - Per-wave EARLY flags: waves 0/1 certify their own 16 cols right after
//    their h-store drain (no syncthreads/tid0 relay on the flag path).
//  - Every consumer wave polls flags directly (no LDS relay), s_sleep(1).
//  - L0->L1: 32-slot ring + flags + lazy back-pressure.
// Ledger of falsified alternatives: R13 poison-poll (-18%), R14 plain+fence
// (-41%), R15 pipelined-poll/all-lane-stores (crash: non-early-clobber async
// asm + compare hoisted past waitcnt), R11 sc0-only sync (broken: ~1ms flag
// propagation). The step cost is cross-XCD latency-bound: ~2 agent RTs +
// laggard-max + 0.8us MFMA = ~5.1us/step.

#define TT 512
#define BB 64
#define HH 1024
#define NWG 256
#define NBH (BB * HH)
#define RING 32

typedef _Float16 half8 __attribute__((ext_vector_type(8)));
typedef _Float16 f16x4 __attribute__((ext_vector_type(4)));
typedef float f32x4 __attribute__((ext_vector_type(4)));
typedef unsigned int u32x4 __attribute__((ext_vector_type(4)));
typedef unsigned long long u64;

#define MFMA16 __builtin_amdgcn_mfma_f32_16x16x32_f16

// ---------------- asm memory helpers (64-bit VGPR-address form) ----------------
__device__ inline u32x4 ldq_plain(const void* p) {
  u32x4 r; u64 a = (u64)(uintptr_t)p;
  asm volatile("global_load_dwordx4 %0, %1, off" : "=v"(r) : "v"(a));
  return r;
}
__device__ inline u32x4 ldq_agent(const void* p) {
  u32x4 r; u64 a = (u64)(uintptr_t)p;
  asm volatile("global_load_dwordx4 %0, %1, off sc0 sc1" : "=v"(r) : "v"(a));
  return r;
}
__device__ inline unsigned ldflag(const void* p) {   // agent-scope flag read
  unsigned r; u64 a = (u64)(uintptr_t)p;
  asm volatile("global_load_dword %0, %1, off sc0 sc1\n\ts_waitcnt vmcnt(0)"
               : "=v"(r) : "v"(a) : "memory");
  return r;
}
__device__ inline void stw(void* p, unsigned v) {    // agent-scope store
  u64 a = (u64)(uintptr_t)p;
  asm volatile("global_store_dword %0, %1, off sc0 sc1" :: "v"(a), "v"(v) : "memory");
}
__device__ inline void vdrain() { asm volatile("s_waitcnt vmcnt(0)" ::: "memory"); }

__device__ inline float fast_sigmoid(float x) { return 1.f / (1.f + __expf(-x)); }
__device__ inline float fast_tanh(float x) {
  float e = __expf(2.f * x);
  return 1.f - 2.f / (e + 1.f);
}
__device__ inline void backoff_sleep(int sl) {   // literal-only s_sleep
  if (sl <= 0) __builtin_amdgcn_s_sleep(1);
  else if (sl == 1) __builtin_amdgcn_s_sleep(2);
  else if (sl == 2) __builtin_amdgcn_s_sleep(4);
  else __builtin_amdgcn_s_sleep(8);
}

// ---------------- prologue kernels ----------------
__global__ void cvt_f32_f16_kernel(const float* __restrict__ src,
                                   _Float16* __restrict__ dst, long n) {
  long i = ((long)blockIdx.x * blockDim.x + threadIdx.x) * 4;
  long stride = (long)gridDim.x * blockDim.x * 4;
  for (long e = i; e < n; e += stride) {
    float4 v = *(const float4*)(src + e);
    f16x4 h;
    h.x = (_Float16)v.x; h.y = (_Float16)v.y;
    h.z = (_Float16)v.z; h.w = (_Float16)v.w;
    *(f16x4*)(dst + e) = h;
  }
}

// wp[tile(192)][kst(64)][lane(64)][8]; element = W[tile*16+(lane&15)][k],
// k = kst*32 + (lane>>4)*8 + sub; kst<32 from Wh, kst>=32 from Wx.
__global__ void cvt_wpack_kernel(const float* __restrict__ Wh,
                                 const float* __restrict__ Wx,
                                 _Float16* __restrict__ wp) {
  int gid = blockIdx.x * 256 + threadIdx.x;
  int lane = gid & 63;
  int kst = (gid >> 6) & 63;
  int tile = gid >> 12;
  int g = tile * 16 + (lane & 15);
  int ko = (lane >> 4) * 8;
  const float* src = (kst < 32) ? (Wh + (long)g * HH + kst * 32 + ko)
                                : (Wx + (long)g * HH + (kst - 32) * 32 + ko);
  half8 h;
#pragma unroll
  for (int j = 0; j < 8; ++j) h[j] = (_Float16)src[j];
  *(half8*)(wp + (((long)tile * 64 + kst) * 64 + lane) * 8) = h;
}

__global__ void init_hf_kernel(const float* __restrict__ h0,
                               _Float16* __restrict__ h0loc,
                               _Float16* __restrict__ h1loc) {
  int i = blockIdx.x * 256 + threadIdx.x;  // grid = 2*B*H/256
  float v = h0[i];
  if (i < NBH) h0loc[i] = (_Float16)v;
  else         h1loc[i - NBH] = (_Float16)v;
}

__global__ void sentinel_kernel(float* out) { out[0] = 12345.0f; }

// ---------------- persistent 2-layer GRU ----------------
__global__ __launch_bounds__(256, 1) void gru_persist(
    const _Float16* __restrict__ x16,
    const _Float16* __restrict__ w0p, const _Float16* __restrict__ w1p,
    const float* __restrict__ bx0, const float* __restrict__ bh0,
    const float* __restrict__ bx1, const float* __restrict__ bh1,
    const float* __restrict__ h0in,
    _Float16* __restrict__ h0loc, _Float16* __restrict__ h1loc,
    _Float16* __restrict__ hist,
    float* __restrict__ out, unsigned* __restrict__ bar)
{
  const int tid = threadIdx.x;
  const int wid = tid >> 6, lane = tid & 63;
  const int wg = blockIdx.x;
  const int lcol = lane & 15;
  const int lk = (lane >> 4) * 8;

  const int grp = wg >> 5;          // 0..7
  const int layer = grp >> 2;
  const int q = grp & 3;
  const int rank = wg & 31;

  __shared__ u32x4 wlds[4][6][4][64];   // 96KB: per-wave kst 12..15 weights
  __shared__ f32x4 red[4][6][64];       // 24KB
  __shared__ f32x4 yshare[2][64];       // 2KB

  unsigned* myf  = bar + grp * 1024;            // 64 slots x 64B stride
  unsigned* l0if = bar + 8192 + q * 1024;       // ring-valid flags (32 slots)
  unsigned* prog = bar + 12288 + q * 1024;      // L1 progress (32 slots)

  // ---- weights: WG owns 32 cols (2 col-tiles) x 3 gates = 6 tiles ----
  const _Float16* wf = layer ? w1p : w0p;
  _Float16* hloc = layer ? h1loc : h0loc;
  half8 wb[6][12];
#pragma unroll
  for (int i = 0; i < 6; ++i) {
    const long tile = (long)((i >> 1) * 64 + rank * 2 + (i & 1));
#pragma unroll
    for (int ks = 0; ks < 12; ++ks)
      wb[i][ks] = *(const half8*)(wf + (tile * 64 + (wid * 16 + ks)) * 512 + lane * 8);
#pragma unroll
    for (int jj = 0; jj < 4; ++jj)
      wlds[wid][i][jj][lane] = *(const u32x4*)(wf + (tile * 64 + (wid * 16 + 12 + jj)) * 512 + lane * 8);
  }

  const int er0 = q * 16 + (lane >> 4) * 4;     // 4 batch rows (global row ids)
  const int col = rank * 32 + wid * 16 + lcol;  // valid for wid<2
  float rbv = 0.f, zbv = 0.f, nhb = 0.f, nxb = 0.f;
  float hreg[4] = {0.f, 0.f, 0.f, 0.f};
  if (wid < 2) {
    const float* bx = layer ? bx1 : bx0;
    const float* bhp = layer ? bh1 : bh0;
    rbv = bhp[col] + bx[col];
    zbv = bhp[HH + col] + bx[HH + col];
    nhb = bhp[2 * HH + col];
    nxb = bx[2 * HH + col];
#pragma unroll
    for (int j = 0; j < 4; ++j)
      hreg[j] = h0in[layer * NBH + (er0 + j) * HH + col];
  }
  __syncthreads();   // wlds ready

  // per-lane byte offset of this wave's A-fragment chunk 0
  const long aoff = (long)(((q * 16 + lcol) * HH) + (wid & 1) * 512 + lk) * 2;

  int lb = 0;   // wave2(L0): lazy lower bound on L1 progress
  for (int t = 0; t < TT; ++t) {
    const int rd = t & 1;
    u32x4 ab[16];

    if (wid < 2) {
      // ---- wait: own group finished step t-1 (both h-waves poll directly) ----
      if (t > 0) {
        for (;;) {
          unsigned f = ldflag(myf + lane * 16);          // 64 slots, 1/lane
          if (__ballot((int)f >= t) == ~0ull) break;
          __builtin_amdgcn_s_sleep(1);
        }
        asm volatile("" ::: "memory");
      }
      const char* ap = (const char*)(hloc + (long)rd * NBH) + aoff;
#pragma unroll
      for (int ks = 0; ks < 16; ++ks) ab[ks] = ldq_agent(ap + ks * 64);
    } else if (layer == 0) {
      const char* ap = (const char*)(x16 + (long)t * NBH) + aoff;
#pragma unroll
      for (int ks = 0; ks < 16; ++ks) ab[ks] = ldq_plain(ap + ks * 64);
    } else {
      // y0[t] = ring slot t+1: both x-waves poll producer flags directly
      for (;;) {
        unsigned f = ldflag(l0if + (lane & 31) * 16);    // 32 slots
        if (__ballot((int)f >= t + 1) == ~0ull) break;
        __builtin_amdgcn_s_sleep(1);
      }
      asm volatile("" ::: "memory");
      const char* ap = (const char*)(hist + (long)((t + 1) & (RING - 1)) * NBH) + aoff;
#pragma unroll
      for (int ks = 0; ks < 16; ++ks) ab[ks] = ldq_agent(ap + ks * 64);
    }
    asm volatile("s_waitcnt vmcnt(0)" ::: "memory");
    __builtin_amdgcn_sched_barrier(0);

    // ---- 96 MFMAs: 6 tiles x 16 ks ----
    f32x4 acc[6] = {};
#pragma unroll
    for (int ks = 0; ks < 12; ++ks) {
      half8 a = __builtin_bit_cast(half8, ab[ks]);
#pragma unroll
      for (int i = 0; i < 6; ++i) acc[i] = MFMA16(a, wb[i][ks], acc[i], 0, 0, 0);
    }
#pragma unroll
    for (int jj = 0; jj < 4; ++jj) {
      half8 a = __builtin_bit_cast(half8, ab[12 + jj]);
#pragma unroll
      for (int i = 0; i < 6; ++i)
        acc[i] = MFMA16(a, __builtin_bit_cast(half8, wlds[wid][i][jj][lane]), acc[i], 0, 0, 0);
    }
#pragma unroll
    for (int i = 0; i < 6; ++i) red[wid][i][lane] = acc[i];
    __syncthreads();   // (A)

    if (wid < 2) {
      const int h = wid;   // col-tile this wave finishes
      f32x4 rs = red[0][h][lane] + red[1][h][lane] + red[2][h][lane] + red[3][h][lane];
      f32x4 zs = red[0][2 + h][lane] + red[1][2 + h][lane] + red[2][2 + h][lane] + red[3][2 + h][lane];
      f32x4 nh = red[0][4 + h][lane] + red[1][4 + h][lane];
      f32x4 nx = red[2][4 + h][lane] + red[3][4 + h][lane];
      char* hdst = (char*)(hloc + (long)(rd ^ 1) * NBH);
      f32x4 hnv;
#pragma unroll
      for (int j = 0; j < 4; ++j) {
        const float rg = fast_sigmoid(rs[j] + rbv);
        const float zg = fast_sigmoid(zs[j] + zbv);
        const float ng = fast_tanh(nx[j] + nxb + rg * (nh[j] + nhb));
        const float hn = (1.f - zg) * ng + zg * hreg[j];
        hreg[j] = hn; hnv[j] = hn;
      }
      yshare[h][lane] = hnv;
#pragma unroll
      for (int j = 0; j < 4; ++j) {
        _Float16 hf = (_Float16)hnv[j];
        unsigned us = (unsigned)__builtin_bit_cast(unsigned short, hf);
        unsigned other = (unsigned)__shfl_xor((int)us, 1);
        if ((lane & 1) == 0)
          stw(hdst + (long)(((er0 + j) * HH) + col) * 2, us | (other << 16));
      }
      vdrain();                          // this wave's h-stores visible (L3)
      if (lane == 0)
        stw(myf + (rank * 2 + wid) * 16, (unsigned)(t + 1));   // EARLY flag
    }
    __syncthreads();   // (B): yshare visible for waves 2/3

    if (layer == 0) {
      if (wid == 2) {
        // ring stores of step t-1 already drained by this step's load-wait
        stw(l0if + rank * 16, (unsigned)t);                // slots <= t valid
        if (t >= RING - 1) {                               // lazy back-pressure
          const int need = t - (RING - 1);
          if (lb < need) {
            int sl = 0;
            for (;;) {
              unsigned f = ldflag(prog + (lane & 31) * 16);
              if (__ballot((int)f >= need + 16) == ~0ull) { lb = need + 16; break; }
              if (__ballot((int)f >= need) == ~0ull) { lb = need; break; }
              backoff_sleep(sl); ++sl;
            }
          }
        }
        char* rbase = (char*)(hist + (long)((t + 1) & (RING - 1)) * NBH);
#pragma unroll
        for (int h2 = 0; h2 < 2; ++h2) {
          f32x4 v = yshare[h2][lane];
          const int coln = rank * 32 + h2 * 16 + lcol;
#pragma unroll
          for (int j = 0; j < 4; ++j) {
            _Float16 hf = (_Float16)v[j];
            unsigned us = (unsigned)__builtin_bit_cast(unsigned short, hf);
            unsigned other = (unsigned)__shfl_xor((int)us, 1);
            if ((lane & 1) == 0)
              stw(rbase + (long)(((er0 + j) * HH) + coln) * 2, us | (other << 16));
          }
        }
      }
    } else {
      if (wid == 2 && lane == 0)
        stw(prog + rank * 16, (unsigned)t);                // L1 progress
      if (wid == 3) {
        float* yo = out + (long)t * NBH;
#pragma unroll
        for (int h2 = 0; h2 < 2; ++h2) {
          f32x4 v = yshare[h2][lane];
          const int coln = rank * 32 + h2 * 16 + lcol;
#pragma unroll
          for (int j = 0; j < 4; ++j) yo[(er0 + j) * HH + coln] = v[j];
        }
      }
    }
  }

  if (layer == 0 && wid == 2) {          // certify final hist slot
    vdrain();
    stw(l0if + rank * 16, (unsigned)TT);
  }
  if (wid < 2) {                         // final hidden states (f32 master)
#pragma unroll
    for (int j = 0; j < 4; ++j)
      out[(long)TT * NBH + (long)layer * NBH + (er0 + j) * HH + col] = hreg[j];
  }
}

// ---------------- launch ----------------
extern "C" void kernel_launch(void* const* d_in, const int* in_sizes, int n_in,
                              void* d_out, int out_size, void* d_ws, size_t ws_size,
                              hipStream_t stream) {
  const float* x   = (const float*)d_in[0];
  const float* h0  = (const float*)d_in[1];
  const float* Wx0 = (const float*)d_in[2];
  const float* bx0 = (const float*)d_in[3];
  const float* Wh0 = (const float*)d_in[4];
  const float* bh0 = (const float*)d_in[5];
  const float* Wx1 = (const float*)d_in[6];
  const float* bx1 = (const float*)d_in[7];
  const float* Wh1 = (const float*)d_in[8];
  const float* bh1 = (const float*)d_in[9];
  float* out = (float*)d_out;

  const long nTBH = (long)TT * BB * HH;
  const long nWP  = (long)192 * 64 * 64 * 8;

  char* p = (char*)d_ws;
  _Float16* x16   = (_Float16*)p;  p += nTBH * 2;              // 67.1 MB
  _Float16* w0p   = (_Float16*)p;  p += nWP * 2;               // 12.6 MB
  _Float16* w1p   = (_Float16*)p;  p += nWP * 2;               // 12.6 MB
  _Float16* hist  = (_Float16*)p;  p += (long)RING * NBH * 2;  // 4.2 MB
  _Float16* h0loc = (_Float16*)p;  p += 2 * (long)NBH * 2;     // 256 KB
  _Float16* h1loc = (_Float16*)p;  p += 2 * (long)NBH * 2;     // 256 KB
  unsigned* bar   = (unsigned*)p;  p += 65536;                 // 64 KB flags
  if ((size_t)(p - (char*)d_ws) > ws_size) {
    sentinel_kernel<<<1, 1, 0, stream>>>(out);
    return;
  }

  (void)hipMemsetAsync(bar, 0, 65536, stream);
  cvt_f32_f16_kernel<<<2048, 256, 0, stream>>>(x, x16, nTBH);
  cvt_wpack_kernel<<<3072, 256, 0, stream>>>(Wh0, Wx0, w0p);
  cvt_wpack_kernel<<<3072, 256, 0, stream>>>(Wh1, Wx1, w1p);
  init_hf_kernel<<<512, 256, 0, stream>>>(h0, h0loc, h1loc);

  void* args[] = {(void*)&x16, (void*)&w0p, (void*)&w1p,
                  (void*)&bx0, (void*)&bh0, (void*)&bx1, (void*)&bh1,
                  (void*)&h0, (void*)&h0loc, (void*)&h1loc, (void*)&hist,
                  (void*)&out, (void*)&bar};
  hipError_t e = hipLaunchCooperativeKernel((const void*)gru_persist,
                                            dim3(NWG), dim3(256), args, 0, stream);
  if (e != hipSuccess) {
    // 256 WGs at 1 WG/CU: co-resident on an idle device even without coop.
    gru_persist<<<NWG, 256, 0, stream>>>(x16, w0p, w1p, bx0, bh0, bx1, bh1,
                                         h0, h0loc, h1loc, hist, out, bar);
  }
}